// Round 1
// baseline (348.205 us; speedup 1.0000x reference)
//
#include <hip/hip_runtime.h>
#include <math.h>

#define ND 11      // node feature dim
#define ED 5       // edge feature dim
#define NL 3       // NNConv layers
#define NSTEPS 3   // Set2Set steps
#define BN_EPS 1e-5f

typedef _Float16 half8 __attribute__((ext_vector_type(8)));
typedef float f32x4 __attribute__((ext_vector_type(4)));

__device__ __forceinline__ float sigm(float x) { return 1.0f / (1.0f + expf(-x)); }

__device__ __forceinline__ half8 to_h8(float4 a, float4 b) {
  half8 r;
  r[0] = (_Float16)a.x; r[1] = (_Float16)a.y; r[2] = (_Float16)a.z; r[3] = (_Float16)a.w;
  r[4] = (_Float16)b.x; r[5] = (_Float16)b.y; r[6] = (_Float16)b.z; r[7] = (_Float16)b.w;
  return r;
}

// ---------------- in-degree (counts as float) ----------------
__global__ void k_deg(const int* __restrict__ dst, float* __restrict__ deg, int E) {
  int e = blockIdx.x * blockDim.x + threadIdx.x;
  if (e < E) atomicAdd(&deg[dst[e]], 1.0f);
}

// ---------------- node encoder: h = relu(x @ W_enc + b) ----------------
__global__ void k_enc(const float* __restrict__ x, const float* __restrict__ W,
                      const float* __restrict__ bias, float* __restrict__ h, int N) {
  int idx = blockIdx.x * blockDim.x + threadIdx.x;
  if (idx >= N * 64) return;
  int n = idx >> 6, j = idx & 63;
  float acc = bias[j];
#pragma unroll
  for (int i = 0; i < ND; ++i) acc = fmaf(x[n * ND + i], W[i * 64 + j], acc);
  h[idx] = fmaxf(acc, 0.0f);
}

// ---------------- edge MLP layer1, transposed output: e1T[k][E] ----------------
__global__ void k_e1T(const float* __restrict__ ea, const float* __restrict__ W,
                      const float* __restrict__ bias, float* __restrict__ e1T, int E) {
  int e = blockIdx.x * blockDim.x + threadIdx.x;
  int k = blockIdx.y;
  if (e >= E) return;
  float acc = bias[k];
#pragma unroll
  for (int i = 0; i < ED; ++i) acc = fmaf(ea[e * ED + i], W[i * 64 + k], acc);
  e1T[(size_t)k * E + e] = fmaxf(acc, 0.0f);
}

// ---------------- pack eW2 (+eb2 as slice 64) into MFMA-B frag-ready f16 ----------------
// w2P[s][f][lane][j], f = nf*2+kf:  value = src_s[(kf*32 + (l>>4)*8 + j)*64 + nf*16 + (l&15)]
__global__ void k_pack(const float* __restrict__ w2, const float* __restrict__ b2,
                       _Float16* __restrict__ w2P) {
  int idx = blockIdx.x * blockDim.x + threadIdx.x;
  if (idx >= 65 * 8 * 64) return;
  int l = idx & 63;
  int f = (idx >> 6) & 7;
  int s = idx >> 9;
  int nf = f >> 1, kf = f & 1;
  const float* srow = (s < 64) ? (w2 + (size_t)s * 4096) : b2;
  int o = nf * 16 + (l & 15);
  int hb = kf * 32 + (l >> 4) * 8;
  half8 v;
#pragma unroll
  for (int j = 0; j < 8; ++j) v[j] = (_Float16)srow[(hb + j) * 64 + o];
  *(half8*)(w2P + (size_t)idx * 8) = v;
}

__device__ __forceinline__ float e1_scalar(const float* __restrict__ e1T, int k, int e, int E) {
  if (k >= 64) return 1.0f;                       // bias slice: coefficient 1
  return (e < E) ? e1T[(size_t)k * E + e] : 0.0f;
}

// ---------------- fused NNConv message + scatter ----------------
// msg[e,o] = sum_k e1[e,k] * (hs[e,:] @ E_k)[o]  (+ bias slice), atomically into agg[dst]
// one wave / block, 64 edges x 64 o, k-split over gridDim.y (4 ranges of 65 slices)
__global__ __launch_bounds__(64) void k_msg(
    const float* __restrict__ e1T, const float* __restrict__ h,
    const int* __restrict__ src, const int* __restrict__ dst,
    const _Float16* __restrict__ w2P, float* __restrict__ agg, int E) {
  const int l = threadIdx.x;
  const int lo = l & 15, lg = l >> 4;
  const int e0 = blockIdx.x * 64;
  const int kbeg = blockIdx.y * 17;
  const int kend = (kbeg + 17 < 65) ? (kbeg + 17) : 65;

  // A-base frags: hs rows (row = l&15), 8 f16 k-elems per frag (slots = lg*8+j; any
  // consistent A/B slot->k bijection contracts identically)
  half8 hsf[4][2];
  int eIdx[4];
#pragma unroll
  for (int m = 0; m < 4; ++m) {
    int e = e0 + m * 16 + lo;
    eIdx[m] = e;
    if (e < E) {
      const float* hr = h + (size_t)src[e] * 64 + lg * 8;
      float4 a0 = *(const float4*)(hr);
      float4 a1 = *(const float4*)(hr + 4);
      float4 b0 = *(const float4*)(hr + 32);
      float4 b1 = *(const float4*)(hr + 36);
      hsf[m][0] = to_h8(a0, a1);
      hsf[m][1] = to_h8(b0, b1);
    } else {
      half8 z = {0, 0, 0, 0, 0, 0, 0, 0};
      hsf[m][0] = z;
      hsf[m][1] = z;
    }
  }

  f32x4 acc[4][4] = {};
  const half8* wp = (const half8*)w2P;  // [65][8][64] half8 units

  half8 Bc[8];
#pragma unroll
  for (int f = 0; f < 8; ++f) Bc[f] = wp[((size_t)kbeg * 8 + f) * 64 + l];
  float sc[4];
#pragma unroll
  for (int m = 0; m < 4; ++m) sc[m] = e1_scalar(e1T, kbeg, eIdx[m], E);

  for (int k = kbeg; k < kend; ++k) {
    half8 Bn[8];
    float sn[4];
    const bool more = (k + 1 < kend);
    if (more) {  // prefetch next slice (compiler pipelines the vmcnt)
#pragma unroll
      for (int f = 0; f < 8; ++f) Bn[f] = wp[((size_t)(k + 1) * 8 + f) * 64 + l];
#pragma unroll
      for (int m = 0; m < 4; ++m) sn[m] = e1_scalar(e1T, k + 1, eIdx[m], E);
    }
#pragma unroll
    for (int m = 0; m < 4; ++m) {
      const _Float16 s16 = (_Float16)sc[m];
      half8 A0 = hsf[m][0] * s16;  // v_pk_mul_f16: fold e1[e,k] into A rows
      half8 A1 = hsf[m][1] * s16;
#pragma unroll
      for (int nf = 0; nf < 4; ++nf) {
        acc[m][nf] = __builtin_amdgcn_mfma_f32_16x16x32_f16(A0, Bc[nf * 2 + 0], acc[m][nf], 0, 0, 0);
        acc[m][nf] = __builtin_amdgcn_mfma_f32_16x16x32_f16(A1, Bc[nf * 2 + 1], acc[m][nf], 0, 0, 0);
      }
    }
    if (more) {
#pragma unroll
      for (int f = 0; f < 8; ++f) Bc[f] = Bn[f];
#pragma unroll
      for (int m = 0; m < 4; ++m) sc[m] = sn[m];
    }
  }

  // epilogue: D layout col = l&15, row = (l>>4)*4 + reg  [m89-verified]
#pragma unroll
  for (int m = 0; m < 4; ++m) {
#pragma unroll
    for (int r = 0; r < 4; ++r) {
      int e = e0 + m * 16 + lg * 4 + r;
      if (e < E) {
        float* ar = agg + (size_t)dst[e] * 64 + lo;
#pragma unroll
        for (int nf = 0; nf < 4; ++nf) atomicAdd(ar + nf * 16, acc[m][nf][r]);
      }
    }
  }
}

// ---------------- hn = agg/deg + h@root + cbias ; accumulate BN stats ----------------
__global__ __launch_bounds__(256) void k_update(
    const float* __restrict__ agg, const float* __restrict__ deg,
    const float* __restrict__ h, const float* __restrict__ root,
    const float* __restrict__ cbias, float* __restrict__ hn,
    float* __restrict__ bnstats, int N) {
  __shared__ float hrow[16][64];
  __shared__ float red[2][256];
  const int tid = threadIdx.x, o = tid & 63, r = tid >> 6;
  const int nb = blockIdx.x * 16;
#pragma unroll
  for (int ii = 0; ii < 4; ++ii) {
    int n = nb + ii * 4 + r;
    hrow[ii * 4 + r][o] = (n < N) ? h[(size_t)n * 64 + o] : 0.0f;
  }
  __syncthreads();
  float acc[4] = {0.f, 0.f, 0.f, 0.f};
  for (int c = 0; c < 64; ++c) {
    float rv = root[c * 64 + o];
#pragma unroll
    for (int ii = 0; ii < 4; ++ii) acc[ii] = fmaf(hrow[ii * 4 + r][c], rv, acc[ii]);
  }
  float s = 0.f, ss = 0.f;
  const float cb = cbias[o];
#pragma unroll
  for (int ii = 0; ii < 4; ++ii) {
    int n = nb + ii * 4 + r;
    if (n < N) {
      float v = acc[ii] + cb + agg[(size_t)n * 64 + o] / fmaxf(deg[n], 1.0f);
      hn[(size_t)n * 64 + o] = v;
      s += v;
      ss += v * v;
    }
  }
  red[0][tid] = s;
  red[1][tid] = ss;
  __syncthreads();
  if (r == 0) {
    float t0 = red[0][o] + red[0][64 + o] + red[0][128 + o] + red[0][192 + o];
    float t1 = red[1][o] + red[1][64 + o] + red[1][128 + o] + red[1][192 + o];
    atomicAdd(&bnstats[o], t0);
    atomicAdd(&bnstats[64 + o], t1);
  }
}

// ---------------- BN(train stats) + relu + residual, in place into h ----------------
__global__ void k_bn(const float* __restrict__ hn, const float* __restrict__ bnstats,
                     const float* __restrict__ gamma, const float* __restrict__ beta,
                     float* __restrict__ h, int N) {
  int idx = blockIdx.x * blockDim.x + threadIdx.x;
  if (idx >= N * 64) return;
  int o = idx & 63;
  float invN = 1.0f / (float)N;
  float mu = bnstats[o] * invN;
  float var = bnstats[64 + o] * invN - mu * mu;
  float y = (hn[idx] - mu) * rsqrtf(var + BN_EPS) * gamma[o] + beta[o];
  h[idx] += fmaxf(y, 0.0f);
}

// ---------------- graph row pointers from sorted batch ----------------
__global__ void k_ptr(const int* __restrict__ batch, int* __restrict__ ptr, int N, int B) {
  int n = blockIdx.x * blockDim.x + threadIdx.x;
  if (n >= N) return;
  int b = batch[n];
  int pb = (n == 0) ? -1 : batch[n - 1];
  for (int g = pb + 1; g <= b; ++g) ptr[g] = n;
  if (n == N - 1)
    for (int g = b + 1; g <= B; ++g) ptr[g] = N;
}

// ---------------- Set2Set LSTM cell (one block per graph) ----------------
__global__ __launch_bounds__(256) void k_lstm(const float* __restrict__ qstar,
                                              float* __restrict__ hl, float* __restrict__ cl,
                                              const float* __restrict__ Wih,
                                              const float* __restrict__ Whh,
                                              const float* __restrict__ bih,
                                              const float* __restrict__ bhh) {
  __shared__ float qs[128];
  __shared__ float hs[64];
  __shared__ float gates[256];
  int b = blockIdx.x, j = threadIdx.x;
  if (j < 128) qs[j] = qstar[b * 128 + j];
  if (j < 64) hs[j] = hl[b * 64 + j];
  __syncthreads();
  float g = bih[j] + bhh[j];
  for (int i = 0; i < 128; ++i) g = fmaf(qs[i], Wih[j * 128 + i], g);
  for (int i = 0; i < 64; ++i) g = fmaf(hs[i], Whh[j * 64 + i], g);
  gates[j] = g;
  __syncthreads();
  if (j < 64) {
    float ig = sigm(gates[j]);
    float fg = sigm(gates[64 + j]);
    float gg = tanhf(gates[128 + j]);
    float og = sigm(gates[192 + j]);
    float c = fg * cl[b * 64 + j] + ig * gg;
    cl[b * 64 + j] = c;
    hl[b * 64 + j] = og * tanhf(c);
  }
}

// ---------------- Set2Set attention + readout (one wave per graph) ----------------
__global__ __launch_bounds__(64) void k_attn(const float* __restrict__ h,
                                             const float* __restrict__ hl,
                                             const int* __restrict__ ptr,
                                             float* __restrict__ qstar) {
  int b = blockIdx.x, o = threadIdx.x;
  int beg = ptr[b], end = ptr[b + 1];
  float q = hl[b * 64 + o];
  float m = -INFINITY;
  for (int n = beg; n < end; ++n) {
    float p = h[(size_t)n * 64 + o] * q;
#pragma unroll
    for (int s = 32; s; s >>= 1) p += __shfl_xor(p, s);
    m = fmaxf(m, p);
  }
  float ssum = 0.f, r = 0.f;
  for (int n = beg; n < end; ++n) {
    float hv = h[(size_t)n * 64 + o];
    float p = hv * q;
#pragma unroll
    for (int s = 32; s; s >>= 1) p += __shfl_xor(p, s);
    float a = expf(p - m);
    ssum += a;
    r = fmaf(a, hv, r);
  }
  qstar[b * 128 + o] = q;
  qstar[b * 128 + 64 + o] = (end > beg) ? (r / ssum) : 0.0f;
}

// ---------------- regression head (one wave per graph) ----------------
__global__ __launch_bounds__(64) void k_head(const float* __restrict__ qstar,
                                             const float* __restrict__ hW1, const float* __restrict__ hb1,
                                             const float* __restrict__ hW2, const float* __restrict__ hb2,
                                             const float* __restrict__ hW3, const float* __restrict__ hb3,
                                             float* __restrict__ out) {
  __shared__ float qs[128];
  __shared__ float z1[64];
  __shared__ float z2[32];
  int b = blockIdx.x, j = threadIdx.x;
  qs[j] = qstar[b * 128 + j];
  qs[64 + j] = qstar[b * 128 + 64 + j];
  __syncthreads();
  float a = hb1[j];
  for (int i = 0; i < 128; ++i) a = fmaf(qs[i], hW1[i * 64 + j], a);
  z1[j] = fmaxf(a, 0.0f);
  __syncthreads();
  if (j < 32) {
    float a2 = hb2[j];
    for (int i = 0; i < 64; ++i) a2 = fmaf(z1[i], hW2[i * 32 + j], a2);
    z2[j] = fmaxf(a2, 0.0f);
  }
  __syncthreads();
  float p = (j < 32) ? z2[j] * hW3[j] : 0.0f;
#pragma unroll
  for (int s = 32; s; s >>= 1) p += __shfl_xor(p, s);
  if (j == 0) out[b] = p + hb3[0];
}

extern "C" void kernel_launch(void* const* d_in, const int* in_sizes, int n_in,
                              void* d_out, int out_size, void* d_ws, size_t ws_size,
                              hipStream_t stream) {
  const float* x = (const float*)d_in[0];
  const int* eidx = (const int*)d_in[1];
  const float* ea = (const float*)d_in[2];
  const int* batch = (const int*)d_in[3];
  const float* Wenc = (const float*)d_in[4];
  const float* benc = (const float*)d_in[5];
  const float* eW1 = (const float*)d_in[6];
  const float* eb1 = (const float*)d_in[7];
  const float* eW2 = (const float*)d_in[8];
  const float* eb2 = (const float*)d_in[9];
  const float* root = (const float*)d_in[10];
  const float* cbias = (const float*)d_in[11];
  const float* gamma = (const float*)d_in[12];
  const float* beta = (const float*)d_in[13];
  const float* Wih = (const float*)d_in[14];
  const float* Whh = (const float*)d_in[15];
  const float* bih = (const float*)d_in[16];
  const float* bhh = (const float*)d_in[17];
  const float* hW1 = (const float*)d_in[18];
  const float* hb1 = (const float*)d_in[19];
  const float* hW2 = (const float*)d_in[20];
  const float* hb2 = (const float*)d_in[21];
  const float* hW3 = (const float*)d_in[22];
  const float* hb3 = (const float*)d_in[23];

  const int N = in_sizes[0] / ND;
  const int E = in_sizes[1] / 2;
  const int B = out_size;
  const int* srcp = eidx;
  const int* dstp = eidx + E;

  // workspace layout (all fp32-aligned)
  float* ws = (float*)d_ws;
  float* deg = ws;                               // N
  float* h = deg + N;                            // N*64
  float* hn = h + (size_t)N * 64;                // N*64
  float* agg = hn + (size_t)N * 64;              // N*64
  float* e1T = agg + (size_t)N * 64;             // 64*E
  _Float16* w2P = (_Float16*)(e1T + (size_t)64 * E);  // 65*8*64*8 f16
  float* bnstats = (float*)(w2P + 65 * 8 * 64 * 8);   // 128
  float* qstar = bnstats + 128;                  // B*128
  float* hl = qstar + (size_t)B * 128;           // B*64
  float* cl = hl + (size_t)B * 64;               // B*64
  int* ptr = (int*)(cl + (size_t)B * 64);        // B+1

  hipMemsetAsync(deg, 0, (size_t)N * sizeof(float), stream);
  k_deg<<<(E + 255) / 256, 256, 0, stream>>>(dstp, deg, E);
  k_enc<<<(N * 64 + 255) / 256, 256, 0, stream>>>(x, Wenc, benc, h, N);
  k_ptr<<<(N + 255) / 256, 256, 0, stream>>>(batch, ptr, N, B);
  hipMemsetAsync(qstar, 0, (size_t)B * 256 * sizeof(float), stream);  // qstar+hl+cl

  for (int l = 0; l < NL; ++l) {
    hipMemsetAsync(agg, 0, (size_t)N * 64 * sizeof(float), stream);
    hipMemsetAsync(bnstats, 0, 128 * sizeof(float), stream);
    dim3 ge((E + 255) / 256, 64);
    k_e1T<<<ge, 256, 0, stream>>>(ea, eW1 + l * ED * 64, eb1 + l * 64, e1T, E);
    k_pack<<<(65 * 8 * 64 + 255) / 256, 256, 0, stream>>>(eW2 + (size_t)l * 64 * 4096,
                                                          eb2 + (size_t)l * 4096, w2P);
    dim3 gm((E + 63) / 64, 4);
    k_msg<<<gm, 64, 0, stream>>>(e1T, h, srcp, dstp, w2P, agg, E);
    k_update<<<(N + 15) / 16, 256, 0, stream>>>(agg, deg, h, root + l * 64 * 64,
                                                cbias + l * 64, hn, bnstats, N);
    k_bn<<<(N * 64 + 255) / 256, 256, 0, stream>>>(hn, bnstats, gamma + l * 64,
                                                   beta + l * 64, h, N);
  }

  for (int s = 0; s < NSTEPS; ++s) {
    k_lstm<<<B, 256, 0, stream>>>(qstar, hl, cl, Wih, Whh, bih, bhh);
    k_attn<<<B, 64, 0, stream>>>(h, hl, ptr, qstar);
  }
  k_head<<<B, 64, 0, stream>>>(qstar, hW1, hb1, hW2, hb2, hW3, hb3, (float*)d_out);
}

// Round 3
// 262.651 us; speedup vs baseline: 1.3257x; 1.3257x over previous
//
#include <hip/hip_runtime.h>
#include <math.h>

#define ND 11      // node feature dim
#define ED 5       // edge feature dim
#define NL 3       // NNConv layers
#define NSTEPS 3   // Set2Set steps
#define BN_EPS 1e-5f
#define KSPLIT 4

typedef _Float16 half8 __attribute__((ext_vector_type(8)));
typedef float f32x4 __attribute__((ext_vector_type(4)));

__device__ __forceinline__ float sigm(float x) { return 1.0f / (1.0f + expf(-x)); }

__device__ __forceinline__ half8 to_h8(float4 a, float4 b) {
  half8 r;
  r[0] = (_Float16)a.x; r[1] = (_Float16)a.y; r[2] = (_Float16)a.z; r[3] = (_Float16)a.w;
  r[4] = (_Float16)b.x; r[5] = (_Float16)b.y; r[6] = (_Float16)b.z; r[7] = (_Float16)b.w;
  return r;
}

// ---------------- zero the accumulator region (replaces 8 memset nodes) ----------------
__global__ void k_zero(float* __restrict__ p, long Z) {
  long i4 = (long)(blockIdx.x * blockDim.x + threadIdx.x) * 4;
  long stride = (long)gridDim.x * blockDim.x * 4;
  for (; i4 + 3 < Z; i4 += stride) *(float4*)(p + i4) = make_float4(0.f, 0.f, 0.f, 0.f);
  if (i4 < Z) for (; i4 < Z; ++i4) p[i4] = 0.f;  // tail
}

// ---------------- node encoder: h = relu(x @ W_enc + b) ----------------
__global__ void k_enc(const float* __restrict__ x, const float* __restrict__ W,
                      const float* __restrict__ bias, float* __restrict__ h, int N) {
  int idx = blockIdx.x * blockDim.x + threadIdx.x;
  if (idx >= N * 64) return;
  int n = idx >> 6, j = idx & 63;
  float acc = bias[j];
#pragma unroll
  for (int i = 0; i < ND; ++i) acc = fmaf(x[n * ND + i], W[i * 64 + j], acc);
  h[idx] = fmaxf(acc, 0.0f);
}

// ---------------- edge MLP layer1 (all 3 layers) + in-degree ----------------
// e1T layout: [l][k][E]
__global__ __launch_bounds__(256) void k_prep(
    const float* __restrict__ ea, const int* __restrict__ dst,
    const float* __restrict__ eW1, const float* __restrict__ eb1,
    float* __restrict__ e1T, float* __restrict__ deg, int E) {
  const int l = blockIdx.y;
  __shared__ float w1[ED * 64];
  __shared__ float b1[64];
  int tid = threadIdx.x;
  for (int i = tid; i < ED * 64; i += 256) w1[i] = eW1[(size_t)l * ED * 64 + i];  // FIX: 320>256
  if (tid < 64) b1[tid] = eb1[l * 64 + tid];
  __syncthreads();
  int e = blockIdx.x * 256 + tid;
  if (e >= E) return;
  float a[ED];
#pragma unroll
  for (int i = 0; i < ED; ++i) a[i] = ea[e * ED + i];
  if (l == 0) atomicAdd(&deg[dst[e]], 1.0f);
  float* outb = e1T + (size_t)l * 64 * E + e;
#pragma unroll 8
  for (int k = 0; k < 64; ++k) {
    float acc = b1[k];
#pragma unroll
    for (int i = 0; i < ED; ++i) acc = fmaf(a[i], w1[i * 64 + k], acc);
    outb[(size_t)k * E] = fmaxf(acc, 0.0f);
  }
}

// ---------------- pack eW2 (+eb2 as slice 64) into MFMA-B frag-ready f16, all layers ----
// w2P[l][s][f][lane][j], f = nf*2+kf:  value = src_s[(kf*32 + (l>>4)*8 + j)*64 + nf*16 + (l&15)]
__global__ void k_pack3(const float* __restrict__ w2, const float* __restrict__ b2,
                        _Float16* __restrict__ w2P) {
  int idx = blockIdx.x * blockDim.x + threadIdx.x;
  if (idx >= 65 * 8 * 64) return;
  int lay = blockIdx.y;
  int l = idx & 63;
  int f = (idx >> 6) & 7;
  int s = idx >> 9;
  int nf = f >> 1, kf = f & 1;
  const float* srow = (s < 64) ? (w2 + (size_t)lay * 64 * 4096 + (size_t)s * 4096)
                               : (b2 + (size_t)lay * 4096);
  int o = nf * 16 + (l & 15);
  int hb = kf * 32 + (l >> 4) * 8;
  half8 v;
#pragma unroll
  for (int j = 0; j < 8; ++j) v[j] = (_Float16)srow[(hb + j) * 64 + o];
  *(half8*)(w2P + ((size_t)lay * 65 * 8 * 64 + idx) * 8) = v;
}

__device__ __forceinline__ float e1_scalar(const float* __restrict__ e1T, int k, int e, int E) {
  if (k >= 64) return 1.0f;                       // bias slice: coefficient 1
  return (e < E) ? e1T[(size_t)k * E + e] : 0.0f;
}

// ---------------- fused NNConv message + scatter ----------------
// 4 waves/block, each wave one 64-edge tile, all waves share the same k range (L1 reuse of B)
__global__ __launch_bounds__(256) void k_msg(
    const float* __restrict__ e1T, const float* __restrict__ h,
    const int* __restrict__ src, const int* __restrict__ dst,
    const _Float16* __restrict__ w2P, float* __restrict__ agg, int E) {
  const int tid = threadIdx.x;
  const int wid = tid >> 6, l = tid & 63;
  const int lo = l & 15, lg = l >> 4;
  const int e0 = (blockIdx.x * 4 + wid) * 64;
  if (e0 >= E) return;  // no barriers below
  const int kbeg = blockIdx.y * 17;
  const int kend = (kbeg + 17 < 65) ? (kbeg + 17) : 65;

  half8 hsf[4][2];
  int eIdx[4];
#pragma unroll
  for (int m = 0; m < 4; ++m) {
    int e = e0 + m * 16 + lo;
    eIdx[m] = e;
    if (e < E) {
      const float* hr = h + (size_t)src[e] * 64 + lg * 8;
      float4 a0 = *(const float4*)(hr);
      float4 a1 = *(const float4*)(hr + 4);
      float4 b0 = *(const float4*)(hr + 32);
      float4 b1 = *(const float4*)(hr + 36);
      hsf[m][0] = to_h8(a0, a1);
      hsf[m][1] = to_h8(b0, b1);
    } else {
      half8 z = {0, 0, 0, 0, 0, 0, 0, 0};
      hsf[m][0] = z;
      hsf[m][1] = z;
    }
  }

  f32x4 acc[4][4] = {};
  const half8* wp = (const half8*)w2P;  // [65][8][64] half8 units

  half8 Bc[8];
#pragma unroll
  for (int f = 0; f < 8; ++f) Bc[f] = wp[((size_t)kbeg * 8 + f) * 64 + l];
  float sc[4];
#pragma unroll
  for (int m = 0; m < 4; ++m) sc[m] = e1_scalar(e1T, kbeg, eIdx[m], E);

  for (int k = kbeg; k < kend; ++k) {
    half8 Bn[8];
    float sn[4];
    const bool more = (k + 1 < kend);
    if (more) {  // prefetch next slice
#pragma unroll
      for (int f = 0; f < 8; ++f) Bn[f] = wp[((size_t)(k + 1) * 8 + f) * 64 + l];
#pragma unroll
      for (int m = 0; m < 4; ++m) sn[m] = e1_scalar(e1T, k + 1, eIdx[m], E);
    }
#pragma unroll
    for (int m = 0; m < 4; ++m) {
      const _Float16 s16 = (_Float16)sc[m];
      half8 A0 = hsf[m][0] * s16;  // v_pk_mul_f16: fold e1[e,k] into A rows
      half8 A1 = hsf[m][1] * s16;
#pragma unroll
      for (int nf = 0; nf < 4; ++nf) {
        acc[m][nf] = __builtin_amdgcn_mfma_f32_16x16x32_f16(A0, Bc[nf * 2 + 0], acc[m][nf], 0, 0, 0);
        acc[m][nf] = __builtin_amdgcn_mfma_f32_16x16x32_f16(A1, Bc[nf * 2 + 1], acc[m][nf], 0, 0, 0);
      }
    }
    if (more) {
#pragma unroll
      for (int f = 0; f < 8; ++f) Bc[f] = Bn[f];
#pragma unroll
      for (int m = 0; m < 4; ++m) sc[m] = sn[m];
    }
  }

  // epilogue: D layout col = l&15, row = (l>>4)*4 + reg
#pragma unroll
  for (int m = 0; m < 4; ++m) {
#pragma unroll
    for (int r = 0; r < 4; ++r) {
      int e = e0 + m * 16 + lg * 4 + r;
      if (e < E) {
        float* ar = agg + (size_t)dst[e] * 64 + lo;
#pragma unroll
        for (int nf = 0; nf < 4; ++nf) atomicAdd(ar + nf * 16, acc[m][nf][r]);
      }
    }
  }
}

// ---------------- hn = agg/deg + h@root + cbias ; accumulate BN stats ----------------
__global__ __launch_bounds__(256) void k_update(
    const float* __restrict__ agg, const float* __restrict__ deg,
    const float* __restrict__ h, const float* __restrict__ root,
    const float* __restrict__ cbias, float* __restrict__ hn,
    float* __restrict__ bnstats, int N) {
  __shared__ float hrow[16][64];
  __shared__ float red[2][256];
  const int tid = threadIdx.x, o = tid & 63, r = tid >> 6;
  const int nb = blockIdx.x * 16;
#pragma unroll
  for (int ii = 0; ii < 4; ++ii) {
    int n = nb + ii * 4 + r;
    hrow[ii * 4 + r][o] = (n < N) ? h[(size_t)n * 64 + o] : 0.0f;
  }
  __syncthreads();
  float acc[4] = {0.f, 0.f, 0.f, 0.f};
  for (int c = 0; c < 64; ++c) {
    float rv = root[c * 64 + o];
#pragma unroll
    for (int ii = 0; ii < 4; ++ii) acc[ii] = fmaf(hrow[ii * 4 + r][c], rv, acc[ii]);
  }
  float s = 0.f, ss = 0.f;
  const float cb = cbias[o];
#pragma unroll
  for (int ii = 0; ii < 4; ++ii) {
    int n = nb + ii * 4 + r;
    if (n < N) {
      float v = acc[ii] + cb + agg[(size_t)n * 64 + o] / fmaxf(deg[n], 1.0f);
      hn[(size_t)n * 64 + o] = v;
      s += v;
      ss += v * v;
    }
  }
  red[0][tid] = s;
  red[1][tid] = ss;
  __syncthreads();
  if (r == 0) {
    float t0 = red[0][o] + red[0][64 + o] + red[0][128 + o] + red[0][192 + o];
    float t1 = red[1][o] + red[1][64 + o] + red[1][128 + o] + red[1][192 + o];
    atomicAdd(&bnstats[o], t0);
    atomicAdd(&bnstats[64 + o], t1);
  }
}

// ---------------- BN(train stats) + relu + residual, in place into h ----------------
__global__ void k_bn(const float* __restrict__ hn, const float* __restrict__ bnstats,
                     const float* __restrict__ gamma, const float* __restrict__ beta,
                     float* __restrict__ h, int N) {
  int idx = blockIdx.x * blockDim.x + threadIdx.x;
  if (idx >= N * 64) return;
  int o = idx & 63;
  float invN = 1.0f / (float)N;
  float mu = bnstats[o] * invN;
  float var = bnstats[64 + o] * invN - mu * mu;
  float y = (hn[idx] - mu) * rsqrtf(var + BN_EPS) * gamma[o] + beta[o];
  h[idx] += fmaxf(y, 0.0f);
}

// ---------------- graph row pointers from sorted batch ----------------
__global__ void k_ptr(const int* __restrict__ batch, int* __restrict__ ptr, int N, int B) {
  int n = blockIdx.x * blockDim.x + threadIdx.x;
  if (n >= N) return;
  int b = batch[n];
  int pb = (n == 0) ? -1 : batch[n - 1];
  for (int g = pb + 1; g <= b; ++g) ptr[g] = n;
  if (n == N - 1)
    for (int g = b + 1; g <= B; ++g) ptr[g] = N;
}

// ---------------- fused Set2Set step: LSTM + attention (+ head on final step) ----------
__global__ __launch_bounds__(256) void k_s2s(
    const float* __restrict__ h, const int* __restrict__ ptr,
    float* __restrict__ qstar, float* __restrict__ hl, float* __restrict__ cl,
    const float* __restrict__ Wih, const float* __restrict__ Whh,
    const float* __restrict__ bih, const float* __restrict__ bhh,
    const float* __restrict__ hW1, const float* __restrict__ hb1,
    const float* __restrict__ hW2, const float* __restrict__ hb2,
    const float* __restrict__ hW3, const float* __restrict__ hb3,
    float* __restrict__ out, int final_step) {
  __shared__ float qs[128];
  __shared__ float hs[64];
  __shared__ float gates[256];
  __shared__ float qv[64];
  __shared__ float redM[4], redS[4];
  __shared__ float redR[4][64];
  __shared__ float qs2[128];
  __shared__ float z1[64], z2[32];
  const int b = blockIdx.x, tid = threadIdx.x;
  const int wid = tid >> 6, lane = tid & 63;

  // ---- LSTM ----
  if (tid < 128) qs[tid] = qstar[b * 128 + tid];
  if (tid < 64) hs[tid] = hl[b * 64 + tid];
  __syncthreads();
  float g = bih[tid] + bhh[tid];
  for (int i = 0; i < 128; ++i) g = fmaf(qs[i], Wih[tid * 128 + i], g);
  for (int i = 0; i < 64; ++i) g = fmaf(hs[i], Whh[tid * 64 + i], g);
  gates[tid] = g;
  __syncthreads();
  if (tid < 64) {
    float ig = sigm(gates[tid]);
    float fg = sigm(gates[64 + tid]);
    float gg = tanhf(gates[128 + tid]);
    float og = sigm(gates[192 + tid]);
    float c = fg * cl[b * 64 + tid] + ig * gg;
    cl[b * 64 + tid] = c;
    float hnew = og * tanhf(c);
    hl[b * 64 + tid] = hnew;
    qv[tid] = hnew;
  }
  __syncthreads();

  // ---- attention (4 waves over nodes) ----
  const int beg = ptr[b], end = ptr[b + 1];
  const float q = qv[lane];
  float mw = -INFINITY;
  for (int n = beg + wid; n < end; n += 4) {
    float p = h[(size_t)n * 64 + lane] * q;
#pragma unroll
    for (int s = 32; s; s >>= 1) p += __shfl_xor(p, s);
    mw = fmaxf(mw, p);
  }
  if (lane == 0) redM[wid] = mw;
  __syncthreads();
  const float m = fmaxf(fmaxf(redM[0], redM[1]), fmaxf(redM[2], redM[3]));
  float ssum = 0.f, racc = 0.f;
  for (int n = beg + wid; n < end; n += 4) {
    float hv = h[(size_t)n * 64 + lane];
    float p = hv * q;
#pragma unroll
    for (int s = 32; s; s >>= 1) p += __shfl_xor(p, s);
    float a = expf(p - m);
    ssum += a;
    racc = fmaf(a, hv, racc);
  }
  if (lane == 0) redS[wid] = ssum;
  redR[wid][lane] = racc;
  __syncthreads();
  if (tid < 64) {
    float rs = redR[0][tid] + redR[1][tid] + redR[2][tid] + redR[3][tid];
    float sd = redS[0] + redS[1] + redS[2] + redS[3];
    float rr = (end > beg) ? rs / sd : 0.0f;
    qstar[b * 128 + tid] = qv[tid];
    qstar[b * 128 + 64 + tid] = rr;
    qs2[tid] = qv[tid];
    qs2[64 + tid] = rr;
  }
  if (!final_step) return;
  __syncthreads();

  // ---- regression head ----
  if (tid < 64) {
    float a = hb1[tid];
    for (int i = 0; i < 128; ++i) a = fmaf(qs2[i], hW1[i * 64 + tid], a);
    z1[tid] = fmaxf(a, 0.0f);
  }
  __syncthreads();
  if (tid < 32) {
    float a2 = hb2[tid];
    for (int i = 0; i < 64; ++i) a2 = fmaf(z1[i], hW2[i * 32 + tid], a2);
    z2[tid] = fmaxf(a2, 0.0f);
  }
  __syncthreads();
  if (tid < 64) {
    float p = (tid < 32) ? z2[tid] * hW3[tid] : 0.0f;
#pragma unroll
    for (int s = 32; s; s >>= 1) p += __shfl_xor(p, s);
    if (tid == 0) out[b] = p + hb3[0];
  }
}

extern "C" void kernel_launch(void* const* d_in, const int* in_sizes, int n_in,
                              void* d_out, int out_size, void* d_ws, size_t ws_size,
                              hipStream_t stream) {
  const float* x = (const float*)d_in[0];
  const int* eidx = (const int*)d_in[1];
  const float* ea = (const float*)d_in[2];
  const int* batch = (const int*)d_in[3];
  const float* Wenc = (const float*)d_in[4];
  const float* benc = (const float*)d_in[5];
  const float* eW1 = (const float*)d_in[6];
  const float* eb1 = (const float*)d_in[7];
  const float* eW2 = (const float*)d_in[8];
  const float* eb2 = (const float*)d_in[9];
  const float* root = (const float*)d_in[10];
  const float* cbias = (const float*)d_in[11];
  const float* gamma = (const float*)d_in[12];
  const float* beta = (const float*)d_in[13];
  const float* Wih = (const float*)d_in[14];
  const float* Whh = (const float*)d_in[15];
  const float* bih = (const float*)d_in[16];
  const float* bhh = (const float*)d_in[17];
  const float* hW1 = (const float*)d_in[18];
  const float* hb1 = (const float*)d_in[19];
  const float* hW2 = (const float*)d_in[20];
  const float* hb2 = (const float*)d_in[21];
  const float* hW3 = (const float*)d_in[22];
  const float* hb3 = (const float*)d_in[23];

  const int N = in_sizes[0] / ND;
  const int E = in_sizes[1] / 2;
  const int B = out_size;
  const int* srcp = eidx;
  const int* dstp = eidx + E;

  // ---- workspace layout: [zeroed region | rest] ----
  float* ws = (float*)d_ws;
  float* deg = ws;                                     // N
  float* agg = deg + N;                                // 3 * N*64
  float* bnstats = agg + (size_t)3 * N * 64;           // 3 * 128
  float* qstar = bnstats + 384;                        // B*128
  float* hl = qstar + (size_t)B * 128;                 // B*64
  float* cl = hl + (size_t)B * 64;                     // B*64
  const long Z = (long)(cl + (size_t)B * 64 - ws);     // zeroed float count
  float* h = cl + (size_t)B * 64;                      // N*64
  float* hn = h + (size_t)N * 64;                      // N*64
  float* e1T = hn + (size_t)N * 64;                    // 3 * 64*E
  _Float16* w2P = (_Float16*)(e1T + (size_t)3 * 64 * E);  // 3 * 65*8*64*8 f16
  int* ptr = (int*)(w2P + (size_t)3 * 65 * 8 * 64 * 8);   // B+1

  k_zero<<<1024, 256, 0, stream>>>(ws, Z);
  k_enc<<<(N * 64 + 255) / 256, 256, 0, stream>>>(x, Wenc, benc, h, N);
  k_ptr<<<(N + 255) / 256, 256, 0, stream>>>(batch, ptr, N, B);
  dim3 gp((E + 255) / 256, NL);
  k_prep<<<gp, 256, 0, stream>>>(ea, dstp, eW1, eb1, e1T, deg, E);
  dim3 gk((65 * 8 * 64 + 255) / 256, NL);
  k_pack3<<<gk, 256, 0, stream>>>(eW2, eb2, w2P);

  for (int l = 0; l < NL; ++l) {
    float* agg_l = agg + (size_t)l * N * 64;
    float* bn_l = bnstats + l * 128;
    const float* e1_l = e1T + (size_t)l * 64 * E;
    const _Float16* w2_l = w2P + (size_t)l * 65 * 8 * 64 * 8;
    dim3 gm((E + 255) / 256, KSPLIT);
    k_msg<<<gm, 256, 0, stream>>>(e1_l, h, srcp, dstp, w2_l, agg_l, E);
    k_update<<<(N + 15) / 16, 256, 0, stream>>>(agg_l, deg, h, root + l * 64 * 64,
                                                cbias + l * 64, hn, bn_l, N);
    k_bn<<<(N * 64 + 255) / 256, 256, 0, stream>>>(hn, bn_l, gamma + l * 64,
                                                   beta + l * 64, h, N);
  }

  for (int s = 0; s < NSTEPS; ++s) {
    k_s2s<<<B, 256, 0, stream>>>(h, ptr, qstar, hl, cl, Wih, Whh, bih, bhh,
                                 hW1, hb1, hW2, hb2, hW3, hb3, (float*)d_out,
                                 (s == NSTEPS - 1) ? 1 : 0);
  }
}